// Round 1
// baseline (1092.282 us; speedup 1.0000x reference)
//
#include <hip/hip_runtime.h>
#include <hip/hip_bf16.h>

#define EPS 1e-5f
#define SLOPE 0.2f

#define NF 16      // frames = T-1
#define NBATCH 16  // batch B
#define NC 512     // channels C (= GEMM N and K)
#define NHW 256    // H*W
#define ND 256     // cond dim D
#define K2 768     // C + D (conv2_w row stride)

__device__ __forceinline__ float lrelu(float v) { return v >= 0.f ? v : SLOPE * v; }

// sent = leaky(bn(cond @ lin_w.T + lin_b))   [B=16, D=256], bn over batch axis
__global__ __launch_bounds__(256) void k_sent(
    const float* __restrict__ cond, const float* __restrict__ lin_w,
    const float* __restrict__ lin_b, const float* __restrict__ gam,
    const float* __restrict__ bet, float* __restrict__ sent) {
  int d = threadIdx.x;  // 256 threads, one output channel each
  float acc[NBATCH];
  float bias = lin_b[d];
#pragma unroll
  for (int b = 0; b < NBATCH; ++b) acc[b] = bias;
  for (int k = 0; k < ND; ++k) {
    float w = lin_w[d * ND + k];
#pragma unroll
    for (int b = 0; b < NBATCH; ++b) acc[b] = fmaf(cond[b * ND + k], w, acc[b]);
  }
  float mu = 0.f;
#pragma unroll
  for (int b = 0; b < NBATCH; ++b) mu += acc[b];
  mu *= (1.f / NBATCH);
  float var = 0.f;
#pragma unroll
  for (int b = 0; b < NBATCH; ++b) { float t = acc[b] - mu; var = fmaf(t, t, var); }
  var *= (1.f / NBATCH);
  float sc = rsqrtf(var + EPS) * gam[d];
  float sh = bet[d] - mu * sc;
#pragma unroll
  for (int b = 0; b < NBATCH; ++b) sent[b * ND + d] = lrelu(fmaf(acc[b], sc, sh));
}

// bias2[b][o] = sum_d sent[b,d] * conv2_w[o, 512+d]
__global__ __launch_bounds__(256) void k_bias2(
    const float* __restrict__ sent, const float* __restrict__ w2,
    float* __restrict__ bias2) {
  int o = blockIdx.x * 256 + threadIdx.x;  // 512 threads total
  float acc[NBATCH];
#pragma unroll
  for (int b = 0; b < NBATCH; ++b) acc[b] = 0.f;
  for (int d = 0; d < ND; ++d) {
    float w = w2[(size_t)o * K2 + NC + d];
#pragma unroll
    for (int b = 0; b < NBATCH; ++b) acc[b] = fmaf(sent[b * ND + d], w, acc[b]);
  }
#pragma unroll
  for (int b = 0; b < NBATCH; ++b) bias2[b * NC + o] = acc[b];
}

// GEMM1: h1[g][b][o][hw] = sum_c (xbar[f+1,b,c,hw]-xbar[f,b,c,hw]) * w1[o][c]
// grid (M/64=64, N/64=8, nb frames), block 256, 64x64 tile, 4x4 per thread
__global__ __launch_bounds__(256) void k_gemm1(
    const float* __restrict__ xbar, const float* __restrict__ w1,
    float* __restrict__ h1, int f0) {
  __shared__ float As[16][64];
  __shared__ float Bs[16][68];
  int g = blockIdx.z;
  int f = f0 + g;
  int m0 = blockIdx.x * 64;
  int n0 = blockIdx.y * 64;
  int b = m0 >> 8;
  int hw0 = m0 & 255;
  int t = threadIdx.x;
  int tm = t & 15, tn = t >> 4;
  int mm = t & 63, kt = t >> 6;        // A staging
  int nn = t >> 2, kq = (t & 3) * 4;   // B staging

  const float* x0 = xbar + ((size_t)f * NBATCH + b) * (NC * NHW) + hw0;
  const float* x1 = x0 + (size_t)NBATCH * NC * NHW;

  float acc[4][4];
#pragma unroll
  for (int i = 0; i < 4; ++i)
#pragma unroll
    for (int j = 0; j < 4; ++j) acc[i][j] = 0.f;

  for (int c0 = 0; c0 < NC; c0 += 16) {
#pragma unroll
    for (int j = 0; j < 4; ++j) {
      int kk = kt * 4 + j;
      size_t off = (size_t)(c0 + kk) * NHW + mm;
      As[kk][mm] = x1[off] - x0[off];
    }
    const float4 wv = *(const float4*)(&w1[(size_t)(n0 + nn) * NC + c0 + kq]);
    Bs[kq + 0][nn] = wv.x;
    Bs[kq + 1][nn] = wv.y;
    Bs[kq + 2][nn] = wv.z;
    Bs[kq + 3][nn] = wv.w;
    __syncthreads();
#pragma unroll
    for (int kk = 0; kk < 16; ++kk) {
      const float4 av = *(const float4*)(&As[kk][tm * 4]);
      const float4 bv = *(const float4*)(&Bs[kk][tn * 4]);
      float a4[4] = {av.x, av.y, av.z, av.w};
      float b4[4] = {bv.x, bv.y, bv.z, bv.w};
#pragma unroll
      for (int i = 0; i < 4; ++i)
#pragma unroll
        for (int j = 0; j < 4; ++j) acc[i][j] = fmaf(a4[i], b4[j], acc[i][j]);
    }
    __syncthreads();
  }
  float* hp = h1 + (((size_t)g * NBATCH + b) * NC + n0) * NHW + hw0;
#pragma unroll
  for (int j = 0; j < 4; ++j) {
    int o = tn * 4 + j;
    float4 v = make_float4(acc[0][j], acc[1][j], acc[2][j], acc[3][j]);
    *(float4*)(&hp[(size_t)o * NHW + tm * 4]) = v;
  }
}

// per (frame, channel) stats over (b,hw): store (scale, shift) for y = x*scale+shift
__global__ __launch_bounds__(256) void k_stats(
    const float* __restrict__ hraw, const float* __restrict__ gam,
    const float* __restrict__ bet, float2* __restrict__ st) {
  int o = blockIdx.x;
  int g = blockIdx.z;
  int t = threadIdx.x;
  const float* p = hraw + (size_t)g * NBATCH * NC * NHW + (size_t)o * NHW + t;
  float s = 0.f, s2 = 0.f;
#pragma unroll
  for (int b = 0; b < NBATCH; ++b) {
    float v = p[(size_t)b * NC * NHW];
    s += v;
    s2 = fmaf(v, v, s2);
  }
#pragma unroll
  for (int off = 32; off; off >>= 1) {
    s += __shfl_down(s, off);
    s2 += __shfl_down(s2, off);
  }
  __shared__ float ls[4], ls2[4];
  int w = t >> 6;
  if ((t & 63) == 0) { ls[w] = s; ls2[w] = s2; }
  __syncthreads();
  if (t == 0) {
    s = ls[0] + ls[1] + ls[2] + ls[3];
    s2 = ls2[0] + ls2[1] + ls2[2] + ls2[3];
    float mu = s * (1.f / 4096.f);
    float var = s2 * (1.f / 4096.f) - mu * mu;
    float sc = rsqrtf(var + EPS) * gam[o];
    st[g * NC + o] = make_float2(sc, bet[o] - mu * sc);
  }
}

// GEMM2: h2[g][b][o][hw] = sum_c lrelu(h1*sc+sh) * w2[o][c] + bias2[b][o]
__global__ __launch_bounds__(256) void k_gemm2(
    const float* __restrict__ h1, const float2* __restrict__ st1,
    const float* __restrict__ w2, const float* __restrict__ bias2,
    float* __restrict__ h2) {
  __shared__ float As[16][64];
  __shared__ float Bs[16][68];
  int g = blockIdx.z;
  int m0 = blockIdx.x * 64;
  int n0 = blockIdx.y * 64;
  int b = m0 >> 8;
  int hw0 = m0 & 255;
  int t = threadIdx.x;
  int tm = t & 15, tn = t >> 4;
  int mm = t & 63, kt = t >> 6;
  int nn = t >> 2, kq = (t & 3) * 4;

  const float* a0 = h1 + ((size_t)g * NBATCH + b) * (NC * NHW) + hw0;

  float acc[4][4];
#pragma unroll
  for (int i = 0; i < 4; ++i)
#pragma unroll
    for (int j = 0; j < 4; ++j) acc[i][j] = 0.f;

  for (int c0 = 0; c0 < NC; c0 += 16) {
#pragma unroll
    for (int j = 0; j < 4; ++j) {
      int kk = kt * 4 + j;
      int c = c0 + kk;
      float2 sst = st1[g * NC + c];
      float v = fmaf(a0[(size_t)c * NHW + mm], sst.x, sst.y);
      As[kk][mm] = lrelu(v);
    }
    const float4 wv = *(const float4*)(&w2[(size_t)(n0 + nn) * K2 + c0 + kq]);
    Bs[kq + 0][nn] = wv.x;
    Bs[kq + 1][nn] = wv.y;
    Bs[kq + 2][nn] = wv.z;
    Bs[kq + 3][nn] = wv.w;
    __syncthreads();
#pragma unroll
    for (int kk = 0; kk < 16; ++kk) {
      const float4 av = *(const float4*)(&As[kk][tm * 4]);
      const float4 bv = *(const float4*)(&Bs[kk][tn * 4]);
      float a4[4] = {av.x, av.y, av.z, av.w};
      float b4[4] = {bv.x, bv.y, bv.z, bv.w};
#pragma unroll
      for (int i = 0; i < 4; ++i)
#pragma unroll
        for (int j = 0; j < 4; ++j) acc[i][j] = fmaf(a4[i], b4[j], acc[i][j]);
    }
    __syncthreads();
  }
  float* hp = h2 + (((size_t)g * NBATCH + b) * NC + n0) * NHW + hw0;
#pragma unroll
  for (int j = 0; j < 4; ++j) {
    int o = n0 + tn * 4 + j;
    float bz = bias2[b * NC + o];
    float4 v = make_float4(acc[0][j] + bz, acc[1][j] + bz, acc[2][j] + bz, acc[3][j] + bz);
    *(float4*)(&hp[(size_t)(tn * 4 + j) * NHW + tm * 4]) = v;
  }
}

// conv3: out[f,b,y*8+x] = sum_{c,ky,kx} lrelu(h2*sc+sh)[b,c,2y+ky,2x+kx] * w3[c,ky,kx]
__global__ __launch_bounds__(256) void k_conv3(
    const float* __restrict__ h2, const float2* __restrict__ st2,
    const float* __restrict__ w3, float* __restrict__ out, int f0) {
  int g = blockIdx.z;
  int b = blockIdx.x;
  int t = threadIdx.x;
  int oi = t >> 2;  // 0..63 output pixel
  int cs = t & 3;   // channel split 0..3
  int y = oi >> 3, x = oi & 7;
  const float* base = h2 + ((size_t)g * NBATCH + b) * (NC * NHW);
  int p00 = (2 * y) * 16 + 2 * x;
  float acc = 0.f;
  for (int c = cs * 128; c < cs * 128 + 128; ++c) {
    float2 sst = st2[g * NC + c];
    const float* pc = base + (size_t)c * NHW;
    const float* wc = w3 + c * 4;
    float v;
    v = lrelu(fmaf(pc[p00], sst.x, sst.y));      acc = fmaf(v, wc[0], acc);
    v = lrelu(fmaf(pc[p00 + 1], sst.x, sst.y));  acc = fmaf(v, wc[1], acc);
    v = lrelu(fmaf(pc[p00 + 16], sst.x, sst.y)); acc = fmaf(v, wc[2], acc);
    v = lrelu(fmaf(pc[p00 + 17], sst.x, sst.y)); acc = fmaf(v, wc[3], acc);
  }
  acc += __shfl_xor(acc, 1);
  acc += __shfl_xor(acc, 2);
  if (cs == 0) out[((size_t)(f0 + g) * NBATCH + b) * 64 + oi] = acc;
}

extern "C" void kernel_launch(void* const* d_in, const int* in_sizes, int n_in,
                              void* d_out, int out_size, void* d_ws, size_t ws_size,
                              hipStream_t stream) {
  const float* cond = (const float*)d_in[0];
  const float* xbar = (const float*)d_in[1];
  const float* lin_w = (const float*)d_in[2];
  const float* lin_b = (const float*)d_in[3];
  const float* bnsg = (const float*)d_in[4];
  const float* bnsb = (const float*)d_in[5];
  const float* w1 = (const float*)d_in[6];
  const float* bn1g = (const float*)d_in[7];
  const float* bn1b = (const float*)d_in[8];
  const float* w2 = (const float*)d_in[9];
  const float* bn2g = (const float*)d_in[10];
  const float* bn2b = (const float*)d_in[11];
  const float* w3 = (const float*)d_in[12];
  float* out = (float*)d_out;

  char* p = (char*)d_ws;
  float* sent = (float*)p;   p += ((NBATCH * ND * 4 + 255) & ~255);
  float* bias2 = (float*)p;  p += ((NBATCH * NC * 4 + 255) & ~255);
  float2* st1 = (float2*)p;  p += ((NF * NC * 8 + 255) & ~255);
  float2* st2 = (float2*)p;  p += ((NF * NC * 8 + 255) & ~255);
  size_t used = (size_t)(p - (char*)d_ws);
  const size_t frame_bytes = (size_t)NBATCH * NC * NHW * 4;  // 8.39 MB
  size_t rem = ws_size > used ? ws_size - used : 0;
  int FB = (int)(rem / (2 * frame_bytes));
  if (FB < 1) FB = 1;
  if (FB > NF) FB = NF;
  float* h1 = (float*)p;
  float* h2 = h1 + (size_t)FB * NBATCH * NC * NHW;

  k_sent<<<1, 256, 0, stream>>>(cond, lin_w, lin_b, bnsg, bnsb, sent);
  k_bias2<<<2, 256, 0, stream>>>(sent, w2, bias2);
  for (int f0 = 0; f0 < NF; f0 += FB) {
    int nb = (NF - f0) < FB ? (NF - f0) : FB;
    k_gemm1<<<dim3(64, 8, nb), 256, 0, stream>>>(xbar, w1, h1, f0);
    k_stats<<<dim3(NC, 1, nb), 256, 0, stream>>>(h1, bn1g, bn1b, st1);
    k_gemm2<<<dim3(64, 8, nb), 256, 0, stream>>>(h1, st1, w2, bias2, h2);
    k_stats<<<dim3(NC, 1, nb), 256, 0, stream>>>(h2, bn2g, bn2b, st2);
    k_conv3<<<dim3(NBATCH, 1, nb), 256, 0, stream>>>(h2, st2, w3, out, f0);
  }
}

// Round 2
// 340.370 us; speedup vs baseline: 3.2091x; 3.2091x over previous
//
#include <hip/hip_runtime.h>
#include <hip/hip_bf16.h>

#define EPS 1e-5f
#define SLOPE 0.2f

#define NF 16      // frames = T-1
#define NBATCH 16  // batch B
#define NC 512     // channels C (= GEMM N and K)
#define NHW 256    // H*W
#define ND 256     // cond dim D
#define K2 768     // C + D (conv2_w row stride)
#define MF 4096    // per-frame GEMM M = B*HW
#define FRAME_ELEMS ((size_t)MF * NC)   // 2,097,152

typedef __attribute__((ext_vector_type(8))) short short8;
typedef __attribute__((ext_vector_type(4))) float float4v;

__device__ __forceinline__ float lrelu(float v) { return v >= 0.f ? v : SLOPE * v; }
__device__ __forceinline__ float b2f(ushort u) { union { float f; uint i; } x; x.i = ((uint)u) << 16; return x.f; }
__device__ __forceinline__ ushort f2b(float f) {
  uint i = __float_as_uint(f);
  return (ushort)((i + 0x7FFFu + ((i >> 16) & 1u)) >> 16);
}
__device__ __forceinline__ void gl16(const ushort* g, ushort* l) {
  __builtin_amdgcn_global_load_lds(
      (const __attribute__((address_space(1))) unsigned int*)g,
      (__attribute__((address_space(3))) unsigned int*)l, 16, 0, 0);
}

// ---------------- sent = leaky(bn(cond @ lin_w.T + lin_b)) [B,D] ----------------
__global__ __launch_bounds__(256) void k_sent(
    const float* __restrict__ cond, const float* __restrict__ lin_w,
    const float* __restrict__ lin_b, const float* __restrict__ gam,
    const float* __restrict__ bet, float* __restrict__ sent) {
  int d = threadIdx.x;
  float acc[NBATCH];
  float bias = lin_b[d];
#pragma unroll
  for (int b = 0; b < NBATCH; ++b) acc[b] = bias;
  for (int k = 0; k < ND; ++k) {
    float w = lin_w[d * ND + k];
#pragma unroll
    for (int b = 0; b < NBATCH; ++b) acc[b] = fmaf(cond[b * ND + k], w, acc[b]);
  }
  float mu = 0.f;
#pragma unroll
  for (int b = 0; b < NBATCH; ++b) mu += acc[b];
  mu *= (1.f / NBATCH);
  float var = 0.f;
#pragma unroll
  for (int b = 0; b < NBATCH; ++b) { float t = acc[b] - mu; var = fmaf(t, t, var); }
  var *= (1.f / NBATCH);
  float sc = rsqrtf(var + EPS) * gam[d];
  float sh = bet[d] - mu * sc;
#pragma unroll
  for (int b = 0; b < NBATCH; ++b) sent[b * ND + d] = lrelu(fmaf(acc[b], sc, sh));
}

// ---------------- bias2[b][o] = sum_d sent[b,d] * conv2_w[o, 512+d] ----------------
__global__ __launch_bounds__(256) void k_bias2(
    const float* __restrict__ sent, const float* __restrict__ w2,
    float* __restrict__ bias2) {
  int o = blockIdx.x * 256 + threadIdx.x;
  float acc[NBATCH];
#pragma unroll
  for (int b = 0; b < NBATCH; ++b) acc[b] = 0.f;
  for (int d = 0; d < ND; ++d) {
    float w = w2[(size_t)o * K2 + NC + d];
#pragma unroll
    for (int b = 0; b < NBATCH; ++b) acc[b] = fmaf(sent[b * ND + d], w, acc[b]);
  }
#pragma unroll
  for (int b = 0; b < NBATCH; ++b) bias2[b * NC + o] = acc[b];
}

// ---------------- weights -> bf16 (w1 full, w2 first 512 cols) ----------------
__global__ __launch_bounds__(256) void k_wcvt(
    const float* __restrict__ w1, const float* __restrict__ w2,
    ushort* __restrict__ w1b, ushort* __restrict__ w2b) {
  int i = blockIdx.x * 256 + threadIdx.x;  // grid 1024 -> 262144
  w1b[i] = f2b(w1[i]);
  int o = i >> 9, c = i & 511;
  w2b[i] = f2b(w2[(size_t)o * K2 + c]);
}

// ---------------- motions: diff + transpose + cvt:  mot[g][m=b*256+hw][c] bf16 ----
__global__ __launch_bounds__(256) void k_mot(
    const float* __restrict__ xbar, ushort* __restrict__ mot, int f0) {
  __shared__ float T[64][65];
  int g = blockIdx.z;
  int f = f0 + g;
  int b = blockIdx.y;
  int hw0 = (blockIdx.x & 3) * 64;
  int c0 = (blockIdx.x >> 2) * 64;
  int t = threadIdx.x;
  int w = t >> 6, l = t & 63;

  const float* x0 = xbar + ((size_t)f * NBATCH + b) * (NC * NHW) + hw0 + l;
  const float* x1 = x0 + (size_t)NBATCH * NC * NHW;
#pragma unroll
  for (int k = 0; k < 16; ++k) {
    int c = 4 * k + w;
    size_t off = (size_t)(c0 + c) * NHW;
    T[c][l] = x1[off] - x0[off];
  }
  __syncthreads();
  ushort* mp = mot + ((size_t)g * MF + b * NHW + hw0) * NC + c0;
#pragma unroll
  for (int k = 0; k < 16; ++k) {
    int hw = 4 * k + w;
    mp[(size_t)hw * NC + l] = f2b(T[l][hw]);
  }
}

// ---------------- MFMA GEMM: H[g][m][o] = A[g][m][k] * W[o][k]^T (+bias2) --------
// 128x128 tile, BK=32, 4 waves (each 64x64), 16x16x32 bf16 MFMA
template <int BIAS>
__global__ __launch_bounds__(256) void k_gemm(
    const ushort* __restrict__ A, const ushort* __restrict__ W,
    const float* __restrict__ bias2, ushort* __restrict__ H) {
  __shared__ ushort lds[8192];  // A: [0,4096) = [128][32], B: [4096,8192)
  int t = threadIdx.x;
  int w = t >> 6, l = t & 63;
  int g = blockIdx.z;
  int m0 = blockIdx.x * 128;
  int n0 = blockIdx.y * 128;
  int wr = w >> 1, wc = w & 1;

  const ushort* Ag = A + ((size_t)g * MF + m0) * NC;
  const ushort* Wg = W + (size_t)n0 * NC;

  float4v acc[4][4];
#pragma unroll
  for (int i = 0; i < 4; ++i)
#pragma unroll
    for (int j = 0; j < 4; ++j) acc[i][j] = (float4v)0.f;

  int s1 = (w * 2 + 0) * 64 + l;
  int s2 = (w * 2 + 1) * 64 + l;

  for (int c0 = 0; c0 < NC; c0 += 32) {
    gl16(Ag + (size_t)(s1 >> 2) * NC + c0 + (s1 & 3) * 8, &lds[s1 * 8]);
    gl16(Ag + (size_t)(s2 >> 2) * NC + c0 + (s2 & 3) * 8, &lds[s2 * 8]);
    gl16(Wg + (size_t)(s1 >> 2) * NC + c0 + (s1 & 3) * 8, &lds[4096 + s1 * 8]);
    gl16(Wg + (size_t)(s2 >> 2) * NC + c0 + (s2 & 3) * 8, &lds[4096 + s2 * 8]);
    __syncthreads();
    short8 af[4], bfr[4];
#pragma unroll
    for (int i = 0; i < 4; ++i)
      af[i] = *(const short8*)&lds[(wr * 64 + i * 16 + (l & 15)) * 32 + (l >> 4) * 8];
#pragma unroll
    for (int j = 0; j < 4; ++j)
      bfr[j] = *(const short8*)&lds[4096 + (wc * 64 + j * 16 + (l & 15)) * 32 + (l >> 4) * 8];
#pragma unroll
    for (int i = 0; i < 4; ++i)
#pragma unroll
      for (int j = 0; j < 4; ++j)
        acc[i][j] = __builtin_amdgcn_mfma_f32_16x16x32_bf16(af[i], bfr[j], acc[i][j], 0, 0, 0);
    __syncthreads();
  }

  // epilogue: per-wave LDS transpose to get coalesced [m][o] bf16 stores
  float bz[4];
#pragma unroll
  for (int fn = 0; fn < 4; ++fn)
    bz[fn] = BIAS ? bias2[(m0 >> 8) * NC + n0 + wc * 64 + fn * 16 + (l & 15)] : 0.f;

  ushort* ep = &lds[w * 1088];  // 16 x 68
  ushort* Hg = H + ((size_t)g * MF + m0 + wr * 64) * NC + n0 + wc * 64;
#pragma unroll
  for (int fm = 0; fm < 4; ++fm) {
#pragma unroll
    for (int fn = 0; fn < 4; ++fn)
#pragma unroll
      for (int j = 0; j < 4; ++j)
        ep[((l >> 4) * 4 + j) * 68 + fn * 16 + (l & 15)] = f2b(acc[fm][fn][j] + bz[fn]);
#pragma unroll
    for (int h = 0; h < 2; ++h) {
      int r = h * 8 + (l >> 3), sl = l & 7;
      short8 v = *(const short8*)&ep[r * 68 + sl * 8];
      *(short8*)&Hg[(size_t)(fm * 16 + r) * NC + sl * 8] = v;
    }
  }
}

// ---------------- stats stage 1: partial sums over 512-row chunks ----------------
__global__ __launch_bounds__(256) void k_stats1(
    const ushort* __restrict__ h, float2* __restrict__ part) {
  int mc = blockIdx.x;  // 0..7
  int g = blockIdx.z;
  int t = threadIdx.x;
  int o0 = t * 2;
  const ushort* p = h + (size_t)g * FRAME_ELEMS + (size_t)mc * 512 * NC + o0;
  float s0 = 0.f, s1 = 0.f, q0 = 0.f, q1 = 0.f;
  for (int m = 0; m < 512; ++m) {
    uint u = *(const uint*)(p + (size_t)m * NC);
    float a = b2f((ushort)(u & 0xFFFF));
    float b = b2f((ushort)(u >> 16));
    s0 += a; q0 = fmaf(a, a, q0);
    s1 += b; q1 = fmaf(b, b, q1);
  }
  float2* pp = part + ((size_t)g * 8 + mc) * NC + o0;
  pp[0] = make_float2(s0, q0);
  pp[1] = make_float2(s1, q1);
}

// ---------------- stats stage 2: finalize (scale, shift) per (g,o) ---------------
__global__ __launch_bounds__(256) void k_stats2(
    const float2* __restrict__ part, const float* __restrict__ gam,
    const float* __restrict__ bet, float2* __restrict__ st) {
  int bi = blockIdx.x;
  int g = bi >> 1;
  int o = (bi & 1) * 256 + threadIdx.x;
  float s = 0.f, q = 0.f;
#pragma unroll
  for (int mc = 0; mc < 8; ++mc) {
    float2 v = part[((size_t)g * 8 + mc) * NC + o];
    s += v.x;
    q += v.y;
  }
  float mu = s * (1.f / 4096.f);
  float var = q * (1.f / 4096.f) - mu * mu;
  float sc = rsqrtf(var + EPS) * gam[o];
  st[g * NC + o] = make_float2(sc, bet[o] - mu * sc);
}

// ---------------- act: a2 = bf16(lrelu(h1*sc+sh)) --------------------------------
__global__ __launch_bounds__(256) void k_act(
    const ushort* __restrict__ h1, const float2* __restrict__ st,
    ushort* __restrict__ a2) {
  int g = blockIdx.z;
  size_t i0 = ((size_t)blockIdx.x * 256 + threadIdx.x) * 8;
  int o0 = (int)(i0 & 511);
  const ushort* src = h1 + (size_t)g * FRAME_ELEMS + i0;
  ushort* dst = a2 + (size_t)g * FRAME_ELEMS + i0;
  short8 v = *(const short8*)src;
  short8 r;
#pragma unroll
  for (int e = 0; e < 8; ++e) {
    float2 ss = st[g * NC + o0 + e];
    float x = fmaf(b2f((ushort)v[e]), ss.x, ss.y);
    r[e] = (short)f2b(lrelu(x));
  }
  *(short8*)dst = r;
}

// ---------------- conv3: 2x2 stride-2, with inline bn+leaky ----------------------
__global__ __launch_bounds__(256) void k_conv3(
    const ushort* __restrict__ h2, const float2* __restrict__ st2,
    const float* __restrict__ w3, float* __restrict__ out, int f0) {
  int g = blockIdx.z;
  int b = blockIdx.x;
  int t = threadIdx.x;
  int oi = t >> 2;  // output pixel 0..63
  int cs = t & 3;   // channel quarter
  int y = oi >> 3, x = oi & 7;
  const ushort* base = h2 + ((size_t)g * MF + b * NHW) * NC;
  int m00 = (2 * y) * 16 + 2 * x;
  float acc = 0.f;
  for (int c8 = cs * 128; c8 < cs * 128 + 128; c8 += 8) {
    short8 v0 = *(const short8*)&base[(size_t)(m00 + 0) * NC + c8];
    short8 v1 = *(const short8*)&base[(size_t)(m00 + 1) * NC + c8];
    short8 v2 = *(const short8*)&base[(size_t)(m00 + 16) * NC + c8];
    short8 v3 = *(const short8*)&base[(size_t)(m00 + 17) * NC + c8];
#pragma unroll
    for (int e = 0; e < 8; ++e) {
      float2 ss = st2[g * NC + c8 + e];
      float4 wv = ((const float4*)w3)[c8 + e];
      acc = fmaf(lrelu(fmaf(b2f((ushort)v0[e]), ss.x, ss.y)), wv.x, acc);
      acc = fmaf(lrelu(fmaf(b2f((ushort)v1[e]), ss.x, ss.y)), wv.y, acc);
      acc = fmaf(lrelu(fmaf(b2f((ushort)v2[e]), ss.x, ss.y)), wv.z, acc);
      acc = fmaf(lrelu(fmaf(b2f((ushort)v3[e]), ss.x, ss.y)), wv.w, acc);
    }
  }
  acc += __shfl_xor(acc, 1);
  acc += __shfl_xor(acc, 2);
  if (cs == 0) out[((size_t)(f0 + g) * NBATCH + b) * 64 + oi] = acc;
}

extern "C" void kernel_launch(void* const* d_in, const int* in_sizes, int n_in,
                              void* d_out, int out_size, void* d_ws, size_t ws_size,
                              hipStream_t stream) {
  const float* cond = (const float*)d_in[0];
  const float* xbar = (const float*)d_in[1];
  const float* lin_w = (const float*)d_in[2];
  const float* lin_b = (const float*)d_in[3];
  const float* bnsg = (const float*)d_in[4];
  const float* bnsb = (const float*)d_in[5];
  const float* w1 = (const float*)d_in[6];
  const float* bn1g = (const float*)d_in[7];
  const float* bn1b = (const float*)d_in[8];
  const float* w2 = (const float*)d_in[9];
  const float* bn2g = (const float*)d_in[10];
  const float* bn2b = (const float*)d_in[11];
  const float* w3 = (const float*)d_in[12];
  float* out = (float*)d_out;

  char* p = (char*)d_ws;
  float* sent = (float*)p;    p += ((NBATCH * ND * 4 + 255) & ~255);
  float* bias2 = (float*)p;   p += ((NBATCH * NC * 4 + 255) & ~255);
  float2* st1 = (float2*)p;   p += ((NF * NC * 8 + 255) & ~255);
  float2* st2 = (float2*)p;   p += ((NF * NC * 8 + 255) & ~255);
  float2* part = (float2*)p;  p += (((size_t)NF * 8 * NC * 8 + 255) & ~255);
  ushort* w1b = (ushort*)p;   p += ((NC * NC * 2 + 255) & ~255);
  ushort* w2b = (ushort*)p;   p += ((NC * NC * 2 + 255) & ~255);
  size_t used = (size_t)(p - (char*)d_ws);
  const size_t frame_bytes = FRAME_ELEMS * 2;  // 4.19 MB bf16
  size_t rem = ws_size > used ? ws_size - used : 0;
  int FB = (int)(rem / (3 * frame_bytes));
  if (FB < 1) FB = 1;
  if (FB > NF) FB = NF;
  ushort* bufA = (ushort*)p;                       // mot, later a2 (aliased)
  ushort* bufB = bufA + (size_t)FB * FRAME_ELEMS;  // h1
  ushort* bufC = bufB + (size_t)FB * FRAME_ELEMS;  // h2

  k_wcvt<<<1024, 256, 0, stream>>>(w1, w2, w1b, w2b);
  k_sent<<<1, 256, 0, stream>>>(cond, lin_w, lin_b, bnsg, bnsb, sent);
  k_bias2<<<2, 256, 0, stream>>>(sent, w2, bias2);

  for (int f0 = 0; f0 < NF; f0 += FB) {
    int nb = (NF - f0) < FB ? (NF - f0) : FB;
    k_mot<<<dim3(32, NBATCH, nb), 256, 0, stream>>>(xbar, bufA, f0);
    k_gemm<0><<<dim3(32, 4, nb), 256, 0, stream>>>(bufA, w1b, nullptr, bufB);
    k_stats1<<<dim3(8, 1, nb), 256, 0, stream>>>(bufB, part);
    k_stats2<<<2 * nb, 256, 0, stream>>>(part, bn1g, bn1b, st1);
    k_act<<<dim3(1024, 1, nb), 256, 0, stream>>>(bufB, st1, bufA);
    k_gemm<1><<<dim3(32, 4, nb), 256, 0, stream>>>(bufA, w2b, bias2, bufC);
    k_stats1<<<dim3(8, 1, nb), 256, 0, stream>>>(bufC, part);
    k_stats2<<<2 * nb, 256, 0, stream>>>(part, bn2g, bn2b, st2);
    k_conv3<<<dim3(NBATCH, 1, nb), 256, 0, stream>>>(bufC, st2, w3, out, f0);
  }
}

// Round 3
// 306.424 us; speedup vs baseline: 3.5646x; 1.1108x over previous
//
#include <hip/hip_runtime.h>
#include <hip/hip_bf16.h>

#define EPS 1e-5f
#define SLOPE 0.2f

#define NF 16      // frames = T-1
#define NBATCH 16  // batch B
#define NC 512     // channels C (= GEMM N and K)
#define NHW 256    // H*W
#define ND 256     // cond dim D
#define K2 768     // C + D (conv2_w row stride)
#define MF 4096    // per-frame GEMM M = B*HW
#define FRAME_ELEMS ((size_t)MF * NC)   // 2,097,152

typedef __attribute__((ext_vector_type(8))) short short8;
typedef __attribute__((ext_vector_type(4))) float float4v;

__device__ __forceinline__ float lrelu(float v) { return v >= 0.f ? v : SLOPE * v; }
__device__ __forceinline__ float b2f(ushort u) { union { float f; uint i; } x; x.i = ((uint)u) << 16; return x.f; }
__device__ __forceinline__ ushort f2b(float f) {
  uint i = __float_as_uint(f);
  return (ushort)((i + 0x7FFFu + ((i >> 16) & 1u)) >> 16);
}
__device__ __forceinline__ void gl16(const ushort* g, ushort* l) {
  __builtin_amdgcn_global_load_lds(
      (const __attribute__((address_space(1))) unsigned int*)g,
      (__attribute__((address_space(3))) unsigned int*)l, 16, 0, 0);
}

// ---------------- sent = leaky(bn(cond @ lin_w.T + lin_b)) [B,D] ----------------
__global__ __launch_bounds__(256) void k_sent(
    const float* __restrict__ cond, const float* __restrict__ lin_w,
    const float* __restrict__ lin_b, const float* __restrict__ gam,
    const float* __restrict__ bet, float* __restrict__ sent) {
  int d = threadIdx.x;
  float acc[NBATCH];
  float bias = lin_b[d];
#pragma unroll
  for (int b = 0; b < NBATCH; ++b) acc[b] = bias;
  for (int k = 0; k < ND; ++k) {
    float w = lin_w[d * ND + k];
#pragma unroll
    for (int b = 0; b < NBATCH; ++b) acc[b] = fmaf(cond[b * ND + k], w, acc[b]);
  }
  float mu = 0.f;
#pragma unroll
  for (int b = 0; b < NBATCH; ++b) mu += acc[b];
  mu *= (1.f / NBATCH);
  float var = 0.f;
#pragma unroll
  for (int b = 0; b < NBATCH; ++b) { float t = acc[b] - mu; var = fmaf(t, t, var); }
  var *= (1.f / NBATCH);
  float sc = rsqrtf(var + EPS) * gam[d];
  float sh = bet[d] - mu * sc;
#pragma unroll
  for (int b = 0; b < NBATCH; ++b) sent[b * ND + d] = lrelu(fmaf(acc[b], sc, sh));
}

// ---------------- bias2[b][o] = sum_d sent[b,d] * conv2_w[o, 512+d] ----------------
__global__ __launch_bounds__(256) void k_bias2(
    const float* __restrict__ sent, const float* __restrict__ w2,
    float* __restrict__ bias2) {
  int o = blockIdx.x * 256 + threadIdx.x;
  float acc[NBATCH];
#pragma unroll
  for (int b = 0; b < NBATCH; ++b) acc[b] = 0.f;
  for (int d = 0; d < ND; ++d) {
    float w = w2[(size_t)o * K2 + NC + d];
#pragma unroll
    for (int b = 0; b < NBATCH; ++b) acc[b] = fmaf(sent[b * ND + d], w, acc[b]);
  }
#pragma unroll
  for (int b = 0; b < NBATCH; ++b) bias2[b * NC + o] = acc[b];
}

// ---------------- weights -> bf16 (w1 full, w2 first 512 cols) ----------------
__global__ __launch_bounds__(256) void k_wcvt(
    const float* __restrict__ w1, const float* __restrict__ w2,
    ushort* __restrict__ w1b, ushort* __restrict__ w2b) {
  int i = blockIdx.x * 256 + threadIdx.x;  // grid 1024 -> 262144
  w1b[i] = f2b(w1[i]);
  int o = i >> 9, c = i & 511;
  w2b[i] = f2b(w2[(size_t)o * K2 + c]);
}

// ---------------- motions: diff + transpose + cvt:  mot[g][m=b*256+hw][c] bf16 ----
// each block covers a (64c x 64hw) patch of one batch item, for a group of up to
// 4 consecutive output frames (5 input frame reads -> 4 diffs)
__global__ __launch_bounds__(256) void k_mot(
    const float* __restrict__ xbar, ushort* __restrict__ mot, int f0, int nb) {
  __shared__ float T[64][65];
  int b = blockIdx.y;
  int hw0 = (blockIdx.x & 3) * 64;
  int c0 = (blockIdx.x >> 2) * 64;
  int t = threadIdx.x;
  int w = t >> 6, l = t & 63;
  int fs = blockIdx.z * 4;                 // relative frame start
  int fe = fs + 4 < nb ? fs + 4 : nb;      // relative frame end

  const float* xp = xbar + ((size_t)(f0 + fs) * NBATCH + b) * (NC * NHW) + hw0 + l;
  float prev[16];
#pragma unroll
  for (int k = 0; k < 16; ++k) prev[k] = xp[(size_t)(c0 + 4 * k + w) * NHW];

  for (int fr = fs; fr < fe; ++fr) {
    const float* xc = xbar + ((size_t)(f0 + fr + 1) * NBATCH + b) * (NC * NHW) + hw0 + l;
    float cur[16];
#pragma unroll
    for (int k = 0; k < 16; ++k) cur[k] = xc[(size_t)(c0 + 4 * k + w) * NHW];
#pragma unroll
    for (int k = 0; k < 16; ++k) T[4 * k + w][l] = cur[k] - prev[k];
    __syncthreads();
    ushort* mp = mot + ((size_t)fr * MF + b * NHW + hw0) * NC + c0;
#pragma unroll
    for (int k = 0; k < 16; ++k) mp[(size_t)(4 * k + w) * NC + l] = f2b(T[l][4 * k + w]);
    __syncthreads();
#pragma unroll
    for (int k = 0; k < 16; ++k) prev[k] = cur[k];
  }
}

// ---------------- MFMA GEMM: H[g][m][o] = A[g][m][k] * W[o][k]^T (+bias2) --------
// 128x128 tile, BK=32, double-buffered LDS (2-phase), 4 waves, 16x16x32 bf16 MFMA.
// Epilogue: fold bias, emit bf16 [m][o] via LDS transpose, and write per-block
// partial (sum, sumsq) per output channel for the BN stats reduction.
template <int BIAS>
__global__ __launch_bounds__(256) void k_gemm(
    const ushort* __restrict__ A, const ushort* __restrict__ W,
    const float* __restrict__ bias2, ushort* __restrict__ H,
    float2* __restrict__ part) {
  __shared__ ushort lds[2][8192];  // per buf: A [128][32] at 0, B [128][32] at 4096
  int t = threadIdx.x;
  int w = t >> 6, l = t & 63;
  int g = blockIdx.z;
  int m0 = blockIdx.x * 128;
  int n0 = blockIdx.y * 128;
  int wr = w >> 1, wc = w & 1;

  const ushort* Ag = A + ((size_t)g * MF + m0) * NC;
  const ushort* Wg = W + (size_t)n0 * NC;

  float4v acc[4][4];
#pragma unroll
  for (int i = 0; i < 4; ++i)
#pragma unroll
    for (int j = 0; j < 4; ++j) acc[i][j] = (float4v)0.f;

  int s1 = (w * 2 + 0) * 64 + l;
  int s2 = (w * 2 + 1) * 64 + l;
  size_t ga1 = (size_t)(s1 >> 2) * NC + (s1 & 3) * 8;
  size_t ga2 = (size_t)(s2 >> 2) * NC + (s2 & 3) * 8;

#define STAGE(buf, c0)                                  \
  do {                                                  \
    gl16(Ag + ga1 + (c0), &lds[buf][s1 * 8]);           \
    gl16(Ag + ga2 + (c0), &lds[buf][s2 * 8]);           \
    gl16(Wg + ga1 + (c0), &lds[buf][4096 + s1 * 8]);    \
    gl16(Wg + ga2 + (c0), &lds[buf][4096 + s2 * 8]);    \
  } while (0)

  STAGE(0, 0);
  asm volatile("s_waitcnt vmcnt(0)" ::: "memory");
  __syncthreads();

  for (int kt = 0; kt < 16; ++kt) {
    int cur = kt & 1;
    if (kt < 15) STAGE(cur ^ 1, (kt + 1) * 32);
    short8 af[4], bfr[4];
#pragma unroll
    for (int i = 0; i < 4; ++i)
      af[i] = *(const short8*)&lds[cur][(wr * 64 + i * 16 + (l & 15)) * 32 + (l >> 4) * 8];
#pragma unroll
    for (int j = 0; j < 4; ++j)
      bfr[j] = *(const short8*)&lds[cur][4096 + (wc * 64 + j * 16 + (l & 15)) * 32 + (l >> 4) * 8];
#pragma unroll
    for (int i = 0; i < 4; ++i)
#pragma unroll
      for (int j = 0; j < 4; ++j)
        acc[i][j] = __builtin_amdgcn_mfma_f32_16x16x32_bf16(af[i], bfr[j], acc[i][j], 0, 0, 0);
    if (kt < 15) {
      asm volatile("s_waitcnt vmcnt(0)" ::: "memory");
      __syncthreads();
    }
  }
#undef STAGE
  __syncthreads();

  // fold bias, accumulate per-channel partial stats
  float bz[4];
#pragma unroll
  for (int fn = 0; fn < 4; ++fn)
    bz[fn] = BIAS ? bias2[(m0 >> 8) * NC + n0 + wc * 64 + fn * 16 + (l & 15)] : 0.f;

  float sv[4], qv[4];
#pragma unroll
  for (int fn = 0; fn < 4; ++fn) {
    float s = 0.f, q = 0.f;
#pragma unroll
    for (int fm = 0; fm < 4; ++fm)
#pragma unroll
      for (int j = 0; j < 4; ++j) {
        float v = acc[fm][fn][j] + bz[fn];
        acc[fm][fn][j] = v;
        s += v;
        q = fmaf(v, v, q);
      }
    s += __shfl_xor(s, 16); s += __shfl_xor(s, 32);
    q += __shfl_xor(q, 16); q += __shfl_xor(q, 32);
    sv[fn] = s; qv[fn] = q;
  }
  if (l < 16) {
    int mb = blockIdx.x * 2 + wr;  // 64-row chunk id (0..63)
    float2* pp = part + ((size_t)g * 64 + mb) * NC + n0 + wc * 64 + l;
#pragma unroll
    for (int fn = 0; fn < 4; ++fn) pp[fn * 16] = make_float2(sv[fn], qv[fn]);
  }

  // epilogue: per-wave LDS transpose to get coalesced [m][o] bf16 stores
  ushort* ep = &lds[0][w * 1088];  // 16 x 68
  ushort* Hg = H + ((size_t)g * MF + m0 + wr * 64) * NC + n0 + wc * 64;
#pragma unroll
  for (int fm = 0; fm < 4; ++fm) {
#pragma unroll
    for (int fn = 0; fn < 4; ++fn)
#pragma unroll
      for (int j = 0; j < 4; ++j)
        ep[((l >> 4) * 4 + j) * 68 + fn * 16 + (l & 15)] = f2b(acc[fm][fn][j]);
#pragma unroll
    for (int h = 0; h < 2; ++h) {
      int r = h * 8 + (l >> 3), sl = l & 7;
      short8 v = *(const short8*)&ep[r * 68 + sl * 8];
      *(short8*)&Hg[(size_t)(fm * 16 + r) * NC + sl * 8] = v;
    }
  }
}

// ---------------- stats finalize: (scale, shift) per (g,o) from 64 partials -----
__global__ __launch_bounds__(256) void k_stats2(
    const float2* __restrict__ part, const float* __restrict__ gam,
    const float* __restrict__ bet, float2* __restrict__ st) {
  int bi = blockIdx.x;
  int g = bi >> 1;
  int o = (bi & 1) * 256 + threadIdx.x;
  float s = 0.f, q = 0.f;
#pragma unroll
  for (int mb = 0; mb < 64; ++mb) {
    float2 v = part[((size_t)g * 64 + mb) * NC + o];
    s += v.x;
    q += v.y;
  }
  float mu = s * (1.f / 4096.f);
  float var = q * (1.f / 4096.f) - mu * mu;
  float sc = rsqrtf(var + EPS) * gam[o];
  st[g * NC + o] = make_float2(sc, bet[o] - mu * sc);
}

// ---------------- act: a2 = bf16(lrelu(h1*sc+sh)) --------------------------------
__global__ __launch_bounds__(256) void k_act(
    const ushort* __restrict__ h1, const float2* __restrict__ st,
    ushort* __restrict__ a2) {
  int g = blockIdx.z;
  size_t i0 = ((size_t)blockIdx.x * 256 + threadIdx.x) * 8;
  int o0 = (int)(i0 & 511);
  const ushort* src = h1 + (size_t)g * FRAME_ELEMS + i0;
  ushort* dst = a2 + (size_t)g * FRAME_ELEMS + i0;
  short8 v = *(const short8*)src;
  short8 r;
#pragma unroll
  for (int e = 0; e < 8; ++e) {
    float2 ss = st[g * NC + o0 + e];
    float x = fmaf(b2f((ushort)v[e]), ss.x, ss.y);
    r[e] = (short)f2b(lrelu(x));
  }
  *(short8*)dst = r;
}

// ---------------- conv3: 2x2 stride-2, with inline bn+leaky ----------------------
__global__ __launch_bounds__(256) void k_conv3(
    const ushort* __restrict__ h2, const float2* __restrict__ st2,
    const float* __restrict__ w3, float* __restrict__ out, int f0) {
  int g = blockIdx.z;
  int b = blockIdx.x;
  int t = threadIdx.x;
  int oi = t >> 2;  // output pixel 0..63
  int cs = t & 3;   // channel quarter
  int y = oi >> 3, x = oi & 7;
  const ushort* base = h2 + ((size_t)g * MF + b * NHW) * NC;
  int m00 = (2 * y) * 16 + 2 * x;
  float acc = 0.f;
  for (int c8 = cs * 128; c8 < cs * 128 + 128; c8 += 8) {
    short8 v0 = *(const short8*)&base[(size_t)(m00 + 0) * NC + c8];
    short8 v1 = *(const short8*)&base[(size_t)(m00 + 1) * NC + c8];
    short8 v2 = *(const short8*)&base[(size_t)(m00 + 16) * NC + c8];
    short8 v3 = *(const short8*)&base[(size_t)(m00 + 17) * NC + c8];
#pragma unroll
    for (int e = 0; e < 8; ++e) {
      float2 ss = st2[g * NC + c8 + e];
      float4 wv = ((const float4*)w3)[c8 + e];
      acc = fmaf(lrelu(fmaf(b2f((ushort)v0[e]), ss.x, ss.y)), wv.x, acc);
      acc = fmaf(lrelu(fmaf(b2f((ushort)v1[e]), ss.x, ss.y)), wv.y, acc);
      acc = fmaf(lrelu(fmaf(b2f((ushort)v2[e]), ss.x, ss.y)), wv.z, acc);
      acc = fmaf(lrelu(fmaf(b2f((ushort)v3[e]), ss.x, ss.y)), wv.w, acc);
    }
  }
  acc += __shfl_xor(acc, 1);
  acc += __shfl_xor(acc, 2);
  if (cs == 0) out[((size_t)(f0 + g) * NBATCH + b) * 64 + oi] = acc;
}

extern "C" void kernel_launch(void* const* d_in, const int* in_sizes, int n_in,
                              void* d_out, int out_size, void* d_ws, size_t ws_size,
                              hipStream_t stream) {
  const float* cond = (const float*)d_in[0];
  const float* xbar = (const float*)d_in[1];
  const float* lin_w = (const float*)d_in[2];
  const float* lin_b = (const float*)d_in[3];
  const float* bnsg = (const float*)d_in[4];
  const float* bnsb = (const float*)d_in[5];
  const float* w1 = (const float*)d_in[6];
  const float* bn1g = (const float*)d_in[7];
  const float* bn1b = (const float*)d_in[8];
  const float* w2 = (const float*)d_in[9];
  const float* bn2g = (const float*)d_in[10];
  const float* bn2b = (const float*)d_in[11];
  const float* w3 = (const float*)d_in[12];
  float* out = (float*)d_out;

  char* p = (char*)d_ws;
  float* sent = (float*)p;    p += ((NBATCH * ND * 4 + 255) & ~255);
  float* bias2 = (float*)p;   p += ((NBATCH * NC * 4 + 255) & ~255);
  float2* st1 = (float2*)p;   p += ((NF * NC * 8 + 255) & ~255);
  float2* st2 = (float2*)p;   p += ((NF * NC * 8 + 255) & ~255);
  float2* part = (float2*)p;  p += (((size_t)NF * 64 * NC * 8 + 255) & ~255);
  ushort* w1b = (ushort*)p;   p += ((NC * NC * 2 + 255) & ~255);
  ushort* w2b = (ushort*)p;   p += ((NC * NC * 2 + 255) & ~255);
  size_t used = (size_t)(p - (char*)d_ws);
  const size_t frame_bytes = FRAME_ELEMS * 2;  // 4.19 MB bf16
  size_t rem = ws_size > used ? ws_size - used : 0;
  int FB = (int)(rem / (3 * frame_bytes));
  if (FB < 1) FB = 1;
  if (FB > NF) FB = NF;
  ushort* bufA = (ushort*)p;                       // mot, later a2 (aliased)
  ushort* bufB = bufA + (size_t)FB * FRAME_ELEMS;  // h1
  ushort* bufC = bufB + (size_t)FB * FRAME_ELEMS;  // h2

  k_wcvt<<<1024, 256, 0, stream>>>(w1, w2, w1b, w2b);
  k_sent<<<1, 256, 0, stream>>>(cond, lin_w, lin_b, bnsg, bnsb, sent);
  k_bias2<<<2, 256, 0, stream>>>(sent, w2, bias2);

  for (int f0 = 0; f0 < NF; f0 += FB) {
    int nb = (NF - f0) < FB ? (NF - f0) : FB;
    int ngrp = (nb + 3) / 4;
    k_mot<<<dim3(32, NBATCH, ngrp), 256, 0, stream>>>(xbar, bufA, f0, nb);
    k_gemm<0><<<dim3(32, 4, nb), 256, 0, stream>>>(bufA, w1b, nullptr, bufB, part);
    k_stats2<<<2 * nb, 256, 0, stream>>>(part, bn1g, bn1b, st1);
    k_act<<<dim3(1024, 1, nb), 256, 0, stream>>>(bufB, st1, bufA);
    k_gemm<1><<<dim3(32, 4, nb), 256, 0, stream>>>(bufA, w2b, bias2, bufC, part);
    k_stats2<<<2 * nb, 256, 0, stream>>>(part, bn2g, bn2b, st2);
    k_conv3<<<dim3(NBATCH, 1, nb), 256, 0, stream>>>(bufC, st2, w3, out, f0);
  }
}

// Round 4
// 279.021 us; speedup vs baseline: 3.9147x; 1.0982x over previous
//
#include <hip/hip_runtime.h>
#include <hip/hip_bf16.h>

#define EPS 1e-5f
#define SLOPE 0.2f

#define NF 16      // frames = T-1
#define NBATCH 16  // batch B
#define NC 512     // channels C (= GEMM N and K)
#define NHW 256    // H*W
#define ND 256     // cond dim D
#define K2 768     // C + D (conv2_w row stride)
#define MF 4096    // per-frame GEMM M = B*HW
#define FRAME_ELEMS ((size_t)MF * NC)   // 2,097,152

typedef __attribute__((ext_vector_type(8))) short short8;
typedef __attribute__((ext_vector_type(4))) float float4v;

__device__ __forceinline__ float lrelu(float v) { return v >= 0.f ? v : SLOPE * v; }
__device__ __forceinline__ float b2f(ushort u) { union { float f; uint i; } x; x.i = ((uint)u) << 16; return x.f; }
__device__ __forceinline__ ushort f2b(float f) {
  uint i = __float_as_uint(f);
  return (ushort)((i + 0x7FFFu + ((i >> 16) & 1u)) >> 16);
}
__device__ __forceinline__ void gl16(const ushort* g, ushort* l) {
  __builtin_amdgcn_global_load_lds(
      (const __attribute__((address_space(1))) unsigned int*)g,
      (__attribute__((address_space(3))) unsigned int*)l, 16, 0, 0);
}

// ---------------- sent = leaky(bn(cond @ lin_w.T + lin_b)) [B,D] ----------------
__global__ __launch_bounds__(64) void k_sent(
    const float* __restrict__ cond, const float* __restrict__ lin_w,
    const float* __restrict__ lin_b, const float* __restrict__ gam,
    const float* __restrict__ bet, float* __restrict__ sent) {
  int d = blockIdx.x * 64 + threadIdx.x;
  float acc[NBATCH];
  float bias = lin_b[d];
#pragma unroll
  for (int b = 0; b < NBATCH; ++b) acc[b] = bias;
  for (int k = 0; k < ND; ++k) {
    float w = lin_w[d * ND + k];
#pragma unroll
    for (int b = 0; b < NBATCH; ++b) acc[b] = fmaf(cond[b * ND + k], w, acc[b]);
  }
  float mu = 0.f;
#pragma unroll
  for (int b = 0; b < NBATCH; ++b) mu += acc[b];
  mu *= (1.f / NBATCH);
  float var = 0.f;
#pragma unroll
  for (int b = 0; b < NBATCH; ++b) { float t = acc[b] - mu; var = fmaf(t, t, var); }
  var *= (1.f / NBATCH);
  float sc = rsqrtf(var + EPS) * gam[d];
  float sh = bet[d] - mu * sc;
#pragma unroll
  for (int b = 0; b < NBATCH; ++b) sent[b * ND + d] = lrelu(fmaf(acc[b], sc, sh));
}

// ---------------- bias2[b][o] = sum_d sent[b,d] * conv2_w[o, 512+d] --------------
__global__ __launch_bounds__(256) void k_bias2(
    const float* __restrict__ sent, const float* __restrict__ w2,
    float* __restrict__ bias2) {
  int o = blockIdx.x * 256 + threadIdx.x;
  float acc[NBATCH];
#pragma unroll
  for (int b = 0; b < NBATCH; ++b) acc[b] = 0.f;
  for (int d = 0; d < ND; ++d) {
    float w = w2[(size_t)o * K2 + NC + d];
#pragma unroll
    for (int b = 0; b < NBATCH; ++b) acc[b] = fmaf(sent[b * ND + d], w, acc[b]);
  }
#pragma unroll
  for (int b = 0; b < NBATCH; ++b) bias2[b * NC + o] = acc[b];
}

// ---------------- weights -> bf16 (w1 full, w2 first 512 cols) -------------------
__global__ __launch_bounds__(256) void k_wcvt(
    const float* __restrict__ w1, const float* __restrict__ w2,
    ushort* __restrict__ w1b, ushort* __restrict__ w2b) {
  int i = blockIdx.x * 256 + threadIdx.x;  // grid 1024 -> 262144
  w1b[i] = f2b(w1[i]);
  int o = i >> 9, c = i & 511;
  w2b[i] = f2b(w2[(size_t)o * K2 + c]);
}

// ---------------- motions: diff + transpose + cvt:  mot[g][m=b*256+hw][c] bf16 ---
__global__ __launch_bounds__(256) void k_mot(
    const float* __restrict__ xbar, ushort* __restrict__ mot, int f0, int nb) {
  __shared__ float T[64][65];
  int b = blockIdx.y;
  int hw0 = (blockIdx.x & 3) * 64;
  int c0 = (blockIdx.x >> 2) * 64;
  int t = threadIdx.x;
  int w = t >> 6, l = t & 63;
  int fs = blockIdx.z * 8;
  int fe = fs + 8 < nb ? fs + 8 : nb;

  const float* xp = xbar + ((size_t)(f0 + fs) * NBATCH + b) * (NC * NHW) + hw0 + l;
  float prev[16];
#pragma unroll
  for (int k = 0; k < 16; ++k) prev[k] = xp[(size_t)(c0 + 4 * k + w) * NHW];

  for (int fr = fs; fr < fe; ++fr) {
    const float* xc = xbar + ((size_t)(f0 + fr + 1) * NBATCH + b) * (NC * NHW) + hw0 + l;
    float cur[16];
#pragma unroll
    for (int k = 0; k < 16; ++k) cur[k] = xc[(size_t)(c0 + 4 * k + w) * NHW];
#pragma unroll
    for (int k = 0; k < 16; ++k) T[4 * k + w][l] = cur[k] - prev[k];
    __syncthreads();
    ushort* mp = mot + ((size_t)fr * MF + b * NHW + hw0) * NC + c0;
#pragma unroll
    for (int k = 0; k < 16; ++k) mp[(size_t)(4 * k + w) * NC + l] = f2b(T[l][4 * k + w]);
    __syncthreads();
#pragma unroll
    for (int k = 0; k < 16; ++k) prev[k] = cur[k];
  }
}

// Shared epilogue: fold bias, partial BN stats, LDS-transpose bf16 store.
__device__ __forceinline__ void gemm_epilogue(
    float4v (&acc)[4][4], ushort* lds0, const float* bias2, int has_bias,
    ushort* __restrict__ H, float2* __restrict__ part,
    int g, int m0, int n0, int w, int l, int wr, int wc) {
  float bz[4];
#pragma unroll
  for (int fn = 0; fn < 4; ++fn)
    bz[fn] = has_bias ? bias2[(m0 >> 8) * NC + n0 + wc * 64 + fn * 16 + (l & 15)] : 0.f;

  float sv[4], qv[4];
#pragma unroll
  for (int fn = 0; fn < 4; ++fn) {
    float s = 0.f, q = 0.f;
#pragma unroll
    for (int fm = 0; fm < 4; ++fm)
#pragma unroll
      for (int j = 0; j < 4; ++j) {
        float v = acc[fm][fn][j] + bz[fn];
        acc[fm][fn][j] = v;
        s += v;
        q = fmaf(v, v, q);
      }
    s += __shfl_xor(s, 16); s += __shfl_xor(s, 32);
    q += __shfl_xor(q, 16); q += __shfl_xor(q, 32);
    sv[fn] = s; qv[fn] = q;
  }
  if (l < 16) {
    int mb = (m0 >> 6) + wr;  // 64-row chunk id (0..63)
    float2* pp = part + ((size_t)g * 64 + mb) * NC + n0 + wc * 64 + l;
#pragma unroll
    for (int fn = 0; fn < 4; ++fn) pp[fn * 16] = make_float2(sv[fn], qv[fn]);
  }

  ushort* ep = &lds0[w * 1088];  // 16 x 68 per wave
  ushort* Hg = H + ((size_t)g * MF + m0 + wr * 64) * NC + n0 + wc * 64;
#pragma unroll
  for (int fm = 0; fm < 4; ++fm) {
#pragma unroll
    for (int fn = 0; fn < 4; ++fn)
#pragma unroll
      for (int j = 0; j < 4; ++j)
        ep[((l >> 4) * 4 + j) * 68 + fn * 16 + (l & 15)] = f2b(acc[fm][fn][j]);
#pragma unroll
    for (int h = 0; h < 2; ++h) {
      int r = h * 8 + (l >> 3), sl = l & 7;
      short8 v = *(const short8*)&ep[r * 68 + sl * 8];
      *(short8*)&Hg[(size_t)(fm * 16 + r) * NC + sl * 8] = v;
    }
  }
}

// ---------------- GEMM1: H = mot @ W1^T. counted-vmcnt pipeline + XOR swizzle ----
__global__ __launch_bounds__(256, 2) void k_gemm1(
    const ushort* __restrict__ A, const ushort* __restrict__ W,
    ushort* __restrict__ H, float2* __restrict__ part) {
  __shared__ ushort lds[2][8192];  // per buf: A [128 units of 16B swz] | B at +4096
  int t = threadIdx.x, w = t >> 6, l = t & 63;
  int g = blockIdx.z, m0 = blockIdx.x * 128, n0 = blockIdx.y * 128;
  int wr = w >> 1, wc = w & 1;
  const ushort* Ag = A + ((size_t)g * MF + m0) * NC;
  const ushort* Wg = W + (size_t)n0 * NC;
  int s1 = w * 128 + l, s2 = s1 + 64;
  // source pre-swizzle: unit v holds k-block (v&3)^((v>>3)&3) of row v>>2
  size_t ga1 = (size_t)(s1 >> 2) * NC + (((s1 & 3) ^ ((s1 >> 3) & 3)) * 8);
  size_t ga2 = (size_t)(s2 >> 2) * NC + (((s2 & 3) ^ ((s2 >> 3) & 3)) * 8);

#define STAGE1(buf, c0)                               \
  do {                                                \
    gl16(Ag + ga1 + (c0), &lds[buf][s1 * 8]);         \
    gl16(Ag + ga2 + (c0), &lds[buf][s2 * 8]);         \
    gl16(Wg + ga1 + (c0), &lds[buf][4096 + s1 * 8]);  \
    gl16(Wg + ga2 + (c0), &lds[buf][4096 + s2 * 8]);  \
  } while (0)

  STAGE1(0, 0);
  STAGE1(1, 32);

  float4v acc[4][4];
#pragma unroll
  for (int i = 0; i < 4; ++i)
#pragma unroll
    for (int j = 0; j < 4; ++j) acc[i][j] = (float4v)0.f;

  int xr = ((l & 15) >> 1) & 3;
  int co = ((l >> 4) ^ xr) * 8;  // swizzled k-block select for reads
  int aoff[4], boff[4];
#pragma unroll
  for (int i = 0; i < 4; ++i) aoff[i] = (wr * 64 + i * 16 + (l & 15)) * 32 + co;
#pragma unroll
  for (int j = 0; j < 4; ++j) boff[j] = 4096 + (wc * 64 + j * 16 + (l & 15)) * 32 + co;

  asm volatile("s_waitcnt vmcnt(0)" ::: "memory");
  __builtin_amdgcn_sched_barrier(0);
  __builtin_amdgcn_s_barrier();
  __builtin_amdgcn_sched_barrier(0);

#pragma unroll
  for (int kt = 0; kt < 16; ++kt) {
    const int cur = kt & 1;
    short8 af[4], bfr[4];
#pragma unroll
    for (int i = 0; i < 4; ++i) af[i] = *(const short8*)&lds[cur][aoff[i]];
#pragma unroll
    for (int j = 0; j < 4; ++j) bfr[j] = *(const short8*)&lds[cur][boff[j]];
    asm volatile("s_waitcnt lgkmcnt(0)" ::: "memory");
    __builtin_amdgcn_sched_barrier(0);
    __builtin_amdgcn_s_barrier();   // lds[cur] fully consumed
    __builtin_amdgcn_sched_barrier(0);
    if (kt < 14) STAGE1(cur, (kt + 2) * 32);
#pragma unroll
    for (int i = 0; i < 4; ++i)
#pragma unroll
      for (int j = 0; j < 4; ++j)
        acc[i][j] = __builtin_amdgcn_mfma_f32_16x16x32_bf16(af[i], bfr[j], acc[i][j], 0, 0, 0);
    if (kt < 15) {
      if (kt < 14) asm volatile("s_waitcnt vmcnt(4)" ::: "memory");
      else         asm volatile("s_waitcnt vmcnt(0)" ::: "memory");
      __builtin_amdgcn_sched_barrier(0);
      __builtin_amdgcn_s_barrier();  // tile kt+1 landed for everyone
      __builtin_amdgcn_sched_barrier(0);
    }
  }
#undef STAGE1
  gemm_epilogue(acc, &lds[0][0], nullptr, 0, H, part, g, m0, n0, w, l, wr, wc);
}

// ---------------- GEMM2: H2 = lrelu(bn1(H1)) @ W2^T + bias2 (act fused in-stage) -
__global__ __launch_bounds__(256, 2) void k_gemm2(
    const ushort* __restrict__ A, const ushort* __restrict__ W,
    const float2* __restrict__ st, const float* __restrict__ bias2,
    ushort* __restrict__ H, float2* __restrict__ part) {
  __shared__ ushort lds[2][8192];
  __shared__ float2 stl[NC];
  int t = threadIdx.x, w = t >> 6, l = t & 63;
  int g = blockIdx.z, m0 = blockIdx.x * 128, n0 = blockIdx.y * 128;
  int wr = w >> 1, wc = w & 1;
  const ushort* Ag = A + ((size_t)g * MF + m0) * NC;
  const ushort* Wg = W + (size_t)n0 * NC;
  int s1 = w * 128 + l, s2 = s1 + 64;
  int kb1 = (s1 & 3) ^ ((s1 >> 3) & 3);
  int kb2 = (s2 & 3) ^ ((s2 >> 3) & 3);
  size_t gb1 = (size_t)(s1 >> 2) * NC + kb1 * 8;
  size_t gb2 = (size_t)(s2 >> 2) * NC + kb2 * 8;
  const ushort* As1 = Ag + gb1;
  const ushort* As2 = Ag + gb2;

#define XFORM(aV, sr, dst)                              \
  do {                                                  \
    uint outw[4];                                       \
    _Pragma("unroll") for (int q = 0; q < 4; ++q) {     \
      uint u = ((const uint*)&(aV))[q];                 \
      float f0 = __uint_as_float(u << 16);              \
      float f1 = __uint_as_float(u & 0xffff0000u);      \
      float x0 = fmaf(f0, sr[2 * q].x, sr[2 * q].y);    \
      float x1 = fmaf(f1, sr[2 * q + 1].x, sr[2 * q + 1].y); \
      x0 = fmaxf(x0, SLOPE * x0);                       \
      x1 = fmaxf(x1, SLOPE * x1);                       \
      outw[q] = ((uint)f2b(x1) << 16) | (uint)f2b(x0);  \
    }                                                   \
    *(uint4*)(dst) = *(const uint4*)outw;               \
  } while (0)

  uint4 asA[2], asB[2];
  // prologue: st->LDS, B tiles 0/1 ->LDS, A-src tiles 0/1 ->regs, drain once.
  gl16((const ushort*)(st + (size_t)g * NC) + t * 8, (ushort*)stl + t * 8);
  gl16(Wg + gb1 + 0, &lds[0][4096 + s1 * 8]);
  gl16(Wg + gb2 + 0, &lds[0][4096 + s2 * 8]);
  gl16(Wg + gb1 + 32, &lds[1][4096 + s1 * 8]);
  gl16(Wg + gb2 + 32, &lds[1][4096 + s2 * 8]);
  uint4 t0A = *(const uint4*)(As1);
  uint4 t0B = *(const uint4*)(As2);
  asA[1] = *(const uint4*)(As1 + 32);
  asB[1] = *(const uint4*)(As2 + 32);

  float4v acc[4][4];
#pragma unroll
  for (int i = 0; i < 4; ++i)
#pragma unroll
    for (int j = 0; j < 4; ++j) acc[i][j] = (float4v)0.f;

  int xr = ((l & 15) >> 1) & 3;
  int co = ((l >> 4) ^ xr) * 8;
  int aoff[4], boff[4];
#pragma unroll
  for (int i = 0; i < 4; ++i) aoff[i] = (wr * 64 + i * 16 + (l & 15)) * 32 + co;
#pragma unroll
  for (int j = 0; j < 4; ++j) boff[j] = 4096 + (wc * 64 + j * 16 + (l & 15)) * 32 + co;

  asm volatile("s_waitcnt vmcnt(0)" ::: "memory");
  __builtin_amdgcn_sched_barrier(0);
  __builtin_amdgcn_s_barrier();
  __builtin_amdgcn_sched_barrier(0);
  {
    float2 sr1[8], sr2[8];
#pragma unroll
    for (int e = 0; e < 8; ++e) { sr1[e] = stl[kb1 * 8 + e]; sr2[e] = stl[kb2 * 8 + e]; }
    XFORM(t0A, sr1, &lds[0][s1 * 8]);
    XFORM(t0B, sr2, &lds[0][s2 * 8]);
  }
  asm volatile("s_waitcnt lgkmcnt(0)" ::: "memory");
  __builtin_amdgcn_sched_barrier(0);
  __builtin_amdgcn_s_barrier();
  __builtin_amdgcn_sched_barrier(0);

#pragma unroll
  for (int kt = 0; kt < 16; ++kt) {
    const int cur = kt & 1;
    short8 af[4], bfr[4];
#pragma unroll
    for (int i = 0; i < 4; ++i) af[i] = *(const short8*)&lds[cur][aoff[i]];
#pragma unroll
    for (int j = 0; j < 4; ++j) bfr[j] = *(const short8*)&lds[cur][boff[j]];
    float2 sr1[8], sr2[8];
    if (kt < 15) {
      int k01 = (kt + 1) * 32 + kb1 * 8;
      int k02 = (kt + 1) * 32 + kb2 * 8;
#pragma unroll
      for (int e = 0; e < 8; ++e) { sr1[e] = stl[k01 + e]; sr2[e] = stl[k02 + e]; }
    }
    asm volatile("s_waitcnt lgkmcnt(0)" ::: "memory");
    __builtin_amdgcn_sched_barrier(0);
    __builtin_amdgcn_s_barrier();   // lds[cur] consumed
    __builtin_amdgcn_sched_barrier(0);
    if (kt < 14) {
      int c2 = (kt + 2) * 32;
      asA[kt & 1] = *(const uint4*)(As1 + c2);
      asB[kt & 1] = *(const uint4*)(As2 + c2);
      gl16(Wg + gb1 + c2, &lds[cur][4096 + s1 * 8]);
      gl16(Wg + gb2 + c2, &lds[cur][4096 + s2 * 8]);
    }
#pragma unroll
    for (int i = 0; i < 4; ++i)
#pragma unroll
      for (int j = 0; j < 4; ++j)
        acc[i][j] = __builtin_amdgcn_mfma_f32_16x16x32_bf16(af[i], bfr[j], acc[i][j], 0, 0, 0);
    if (kt < 15) {
      if (kt < 14) asm volatile("s_waitcnt vmcnt(4)" ::: "memory");
      else         asm volatile("s_waitcnt vmcnt(0)" ::: "memory");
      __builtin_amdgcn_sched_barrier(0);
      // transform tile kt+1 into lds[cur^1] A-half
      XFORM(asA[(kt + 1) & 1], sr1, &lds[cur ^ 1][s1 * 8]);
      XFORM(asB[(kt + 1) & 1], sr2, &lds[cur ^ 1][s2 * 8]);
      asm volatile("s_waitcnt lgkmcnt(0)" ::: "memory");
      __builtin_amdgcn_sched_barrier(0);
      __builtin_amdgcn_s_barrier();
      __builtin_amdgcn_sched_barrier(0);
    }
  }
#undef XFORM
  gemm_epilogue(acc, &lds[0][0], bias2, 1, H, part, g, m0, n0, w, l, wr, wc);
}

// ---------------- stats finalize: (scale, shift) per (g,o) from 64 partials ------
__global__ __launch_bounds__(256) void k_stats2(
    const float2* __restrict__ part, const float* __restrict__ gam,
    const float* __restrict__ bet, float2* __restrict__ st) {
  int bi = blockIdx.x;
  int g = bi >> 1;
  int o = (bi & 1) * 256 + threadIdx.x;
  float s = 0.f, q = 0.f;
#pragma unroll
  for (int mb = 0; mb < 64; ++mb) {
    float2 v = part[((size_t)g * 64 + mb) * NC + o];
    s += v.x;
    q += v.y;
  }
  float mu = s * (1.f / 4096.f);
  float var = q * (1.f / 4096.f) - mu * mu;
  float sc = rsqrtf(var + EPS) * gam[o];
  st[g * NC + o] = make_float2(sc, bet[o] - mu * sc);
}

// ---------------- conv3: 2x2 stride-2, with inline bn+leaky ----------------------
__global__ __launch_bounds__(256) void k_conv3(
    const ushort* __restrict__ h2, const float2* __restrict__ st2,
    const float* __restrict__ w3, float* __restrict__ out, int f0) {
  int g = blockIdx.z;
  int b = blockIdx.x;
  int t = threadIdx.x;
  int oi = t >> 2;  // output pixel 0..63
  int cs = t & 3;   // channel quarter
  int y = oi >> 3, x = oi & 7;
  const ushort* base = h2 + ((size_t)g * MF + b * NHW) * NC;
  int m00 = (2 * y) * 16 + 2 * x;
  float acc = 0.f;
  for (int c8 = cs * 128; c8 < cs * 128 + 128; c8 += 8) {
    short8 v0 = *(const short8*)&base[(size_t)(m00 + 0) * NC + c8];
    short8 v1 = *(const short8*)&base[(size_t)(m00 + 1) * NC + c8];
    short8 v2 = *(const short8*)&base[(size_t)(m00 + 16) * NC + c8];
    short8 v3 = *(const short8*)&base[(size_t)(m00 + 17) * NC + c8];
#pragma unroll
    for (int e = 0; e < 8; ++e) {
      float2 ss = st2[g * NC + c8 + e];
      float4 wv = ((const float4*)w3)[c8 + e];
      acc = fmaf(lrelu(fmaf(b2f((ushort)v0[e]), ss.x, ss.y)), wv.x, acc);
      acc = fmaf(lrelu(fmaf(b2f((ushort)v1[e]), ss.x, ss.y)), wv.y, acc);
      acc = fmaf(lrelu(fmaf(b2f((ushort)v2[e]), ss.x, ss.y)), wv.z, acc);
      acc = fmaf(lrelu(fmaf(b2f((ushort)v3[e]), ss.x, ss.y)), wv.w, acc);
    }
  }
  acc += __shfl_xor(acc, 1);
  acc += __shfl_xor(acc, 2);
  if (cs == 0) out[((size_t)(f0 + g) * NBATCH + b) * 64 + oi] = acc;
}

extern "C" void kernel_launch(void* const* d_in, const int* in_sizes, int n_in,
                              void* d_out, int out_size, void* d_ws, size_t ws_size,
                              hipStream_t stream) {
  const float* cond = (const float*)d_in[0];
  const float* xbar = (const float*)d_in[1];
  const float* lin_w = (const float*)d_in[2];
  const float* lin_b = (const float*)d_in[3];
  const float* bnsg = (const float*)d_in[4];
  const float* bnsb = (const float*)d_in[5];
  const float* w1 = (const float*)d_in[6];
  const float* bn1g = (const float*)d_in[7];
  const float* bn1b = (const float*)d_in[8];
  const float* w2 = (const float*)d_in[9];
  const float* bn2g = (const float*)d_in[10];
  const float* bn2b = (const float*)d_in[11];
  const float* w3 = (const float*)d_in[12];
  float* out = (float*)d_out;

  char* p = (char*)d_ws;
  float* sent = (float*)p;    p += ((NBATCH * ND * 4 + 255) & ~255);
  float* bias2 = (float*)p;   p += ((NBATCH * NC * 4 + 255) & ~255);
  float2* st1 = (float2*)p;   p += ((NF * NC * 8 + 255) & ~255);
  float2* st2 = (float2*)p;   p += ((NF * NC * 8 + 255) & ~255);
  float2* part = (float2*)p;  p += (((size_t)NF * 64 * NC * 8 + 255) & ~255);
  ushort* w1b = (ushort*)p;   p += ((NC * NC * 2 + 255) & ~255);
  ushort* w2b = (ushort*)p;   p += ((NC * NC * 2 + 255) & ~255);
  size_t used = (size_t)(p - (char*)d_ws);
  const size_t frame_bytes = FRAME_ELEMS * 2;  // 4.19 MB bf16
  size_t rem = ws_size > used ? ws_size - used : 0;
  int FB = (int)(rem / (3 * frame_bytes));
  if (FB < 1) FB = 1;
  if (FB > NF) FB = NF;
  ushort* bufA = (ushort*)p;                       // mot
  ushort* bufB = bufA + (size_t)FB * FRAME_ELEMS;  // h1
  ushort* bufC = bufB + (size_t)FB * FRAME_ELEMS;  // h2

  k_wcvt<<<1024, 256, 0, stream>>>(w1, w2, w1b, w2b);
  k_sent<<<4, 64, 0, stream>>>(cond, lin_w, lin_b, bnsg, bnsb, sent);
  k_bias2<<<2, 256, 0, stream>>>(sent, w2, bias2);

  for (int f0 = 0; f0 < NF; f0 += FB) {
    int nb = (NF - f0) < FB ? (NF - f0) : FB;
    int ngrp = (nb + 7) / 8;
    k_mot<<<dim3(32, NBATCH, ngrp), 256, 0, stream>>>(xbar, bufA, f0, nb);
    k_gemm1<<<dim3(32, 4, nb), 256, 0, stream>>>(bufA, w1b, bufB, part);
    k_stats2<<<2 * nb, 256, 0, stream>>>(part, bn1g, bn1b, st1);
    k_gemm2<<<dim3(32, 4, nb), 256, 0, stream>>>(bufB, w2b, st1, bias2, bufC, part);
    k_stats2<<<2 * nb, 256, 0, stream>>>(part, bn2g, bn2b, st2);
    k_conv3<<<dim3(NBATCH, 1, nb), 256, 0, stream>>>(bufC, st2, w3, out, f0);
  }
}